// Round 6
// baseline (2896.982 us; speedup 1.0000x reference)
//
#include <hip/hip_runtime.h>
#include <hip/hip_bf16.h>

#define N_USERS 100000
#define E_HYPER 50000
#define NNZ_E   800000
#define T_STEPS 8
#define DIM     64

#define CAP_E   48
#define CAP_N   36

#define TR_BLOCKS  1024
#define GE_BLOCKS  1563
#define GNF_BLOCKS 1563
#define ZERO_BLKS  147

#define SC_PARTS   8
#define SC_SUB     256
#define SC_BLOCKS  (SC_PARTS * SC_SUB)   // 2048
#define SC_CHUNK   (NNZ_E / SC_SUB)      // 3125
#define E_SLICE    (E_HYPER / SC_PARTS)  // 6250
#define N_SLICE    (N_USERS / SC_PARTS)  // 12500

typedef __bf16 bf16x8 __attribute__((ext_vector_type(8)));
typedef float  f32x4  __attribute__((ext_vector_type(4)));

// ---------------------------------------------------------------------------
__device__ __forceinline__ float ld_in(const void* p, size_t i, int f32)
{
    return f32 ? ((const float*)p)[i]
               : __bfloat162float(((const __hip_bfloat16*)p)[i]);
}

__device__ __forceinline__ void st_carry(void* out, float* cws, size_t i,
                                         int f, int use_ws, float v)
{
    if (f) { ((float*)out)[i] = v; return; }
    if (use_ws) { cws[i] = v; return; }
    ((__hip_bfloat16*)out)[i] = __float2bfloat16(v);
}

// ---------------------------------------------------------------------------
// Kernel 0: input dtype detector
// ---------------------------------------------------------------------------
__global__ void k_detect(const unsigned short* __restrict__ raw, int* __restrict__ flag)
{
    __shared__ int cnt;
    if (threadIdx.x == 0) cnt = 0;
    __syncthreads();
    int c = 0;
    for (int i = threadIdx.x; i < 4096; i += blockDim.x) {
        int e = (raw[i] >> 7) & 0xFF;
        if (e > 126) c++;
    }
    atomicAdd(&cnt, c);
    __syncthreads();
    if (threadIdx.x == 0) *flag = (cnt > 64) ? 1 : 0;
}

// ---------------------------------------------------------------------------
// Kernel 0b: params -> fp32 staging
// st: W[0,4096) b[4096,4160) w1[4160,8256) b1[8256,8320) w2[8320,8384) b2[8384]
// ---------------------------------------------------------------------------
__global__ void k_convert_params(
    const void* W, const void* b, const void* w1, const void* b1,
    const void* w2, const void* b2, const int* __restrict__ flag,
    float* __restrict__ st)
{
    int f = *flag;
    int i = blockIdx.x * blockDim.x + threadIdx.x;
    if (i < 4096)          st[i] = ld_in(W,  i,        f);
    else if (i < 4160)     st[i] = ld_in(b,  i - 4096, f);
    else if (i < 8256)     st[i] = ld_in(w1, i - 4160, f);
    else if (i < 8320)     st[i] = ld_in(b1, i - 8256, f);
    else if (i < 8384)     st[i] = ld_in(w2, i - 8320, f);
    else if (i == 8384)    st[i] = ld_in(b2, 0,        f);
}

// ---------------------------------------------------------------------------
// Padded atomic-append (XCD-partitioned writes). counts slab layout:
// [0,E_HYPER) per-hyperedge, [E_HYPER,+N_USERS) per-node.
// ---------------------------------------------------------------------------
__device__ __forceinline__ void appendE_body(
    const int* __restrict__ nodes, const int* __restrict__ hyper,
    int* __restrict__ cnt, int* __restrict__ sn_pad, int bid, int tid)
{
    int part = bid & (SC_PARTS - 1);
    int sub  = bid >> 3;
    int elo  = part * E_SLICE;
    int i0   = sub * SC_CHUNK;
    for (int i = i0 + tid; i < i0 + SC_CHUNK; i += 256) {
        int hy = hyper[i];
        if ((unsigned)(hy - elo) < (unsigned)E_SLICE) {
            int r = atomicAdd(&cnt[hy], 1);
            if (r < CAP_E) sn_pad[hy * CAP_E + r] = nodes[i];
        }
    }
}

__device__ __forceinline__ void appendN_body(
    const int* __restrict__ nodes, const int* __restrict__ hyper,
    int* __restrict__ cnt, int* __restrict__ sh_pad, int bid, int tid)
{
    int part = bid & (SC_PARTS - 1);
    int sub  = bid >> 3;
    int nlo  = part * N_SLICE;
    int i0   = sub * SC_CHUNK;
    for (int i = i0 + tid; i < i0 + SC_CHUNK; i += 256) {
        int nd = nodes[i];
        if ((unsigned)(nd - nlo) < (unsigned)N_SLICE) {
            int r = atomicAdd(&cnt[E_HYPER + nd], 1);
            if (r < CAP_N) sh_pad[nd * CAP_N + r] = hyper[i];
        }
    }
}

__device__ __forceinline__ void zero_body(int* __restrict__ buf, int b, int tid)
{
    int idx = b * 256 + tid;
    if (idx < 150000 / 4) ((int4*)buf)[idx] = make_int4(0, 0, 0, 0);
}

// ---------------------------------------------------------------------------
// gather_e body (padded CSR, 8 segments/wave)
// ---------------------------------------------------------------------------
__device__ __forceinline__ void ge_body(
    const __hip_bfloat16* __restrict__ h,
    const int* __restrict__ sn_pad, const int* __restrict__ cnt_e,
    __hip_bfloat16* __restrict__ e, int bid, int tid)
{
    int lane = tid & 63;
    int wid = bid * 4 + (tid >> 6);
    int nW  = GE_BLOCKS * 4;
    for (int s0 = wid * 8; s0 < E_HYPER; s0 += nW * 8) {
        int pos[8], end8[8], cnt8[8]; float acc[8];
#pragma unroll
        for (int c = 0; c < 8; ++c) {
            int sg = s0 + c;
            int cc = (sg < E_HYPER) ? cnt_e[sg] : 0;
            cnt8[c] = cc;
            pos[c]  = sg * CAP_E;
            end8[c] = pos[c] + min(cc, CAP_E);
            acc[c]  = 0.f;
        }
        while (true) {
            bool any = false;
#pragma unroll
            for (int c = 0; c < 8; ++c) any = any || (pos[c] < end8[c]);
            if (!any) break;
            int id[8];
#pragma unroll
            for (int c = 0; c < 8; ++c)
                if (pos[c] < end8[c]) id[c] = sn_pad[pos[c]];
#pragma unroll
            for (int c = 0; c < 8; ++c)
                if (pos[c] < end8[c]) {
                    acc[c] += __bfloat162float(h[(size_t)id[c] * DIM + lane]);
                    pos[c]++;
                }
        }
#pragma unroll
        for (int c = 0; c < 8; ++c) {
            int sg = s0 + c;
            if (sg < E_HYPER)
                e[(size_t)sg * DIM + lane] =
                    __float2bfloat16(acc[c] / (float)max(cnt8[c], 1));
        }
    }
}

// ---------------------------------------------------------------------------
// fuse tile: ONE 16-row tile at rows [row0,row0+16), dy from LDS (stride 68)
// ---------------------------------------------------------------------------
__device__ __forceinline__ void fu_tile(
    void* __restrict__ dout, float* __restrict__ cws,
    const float* __restrict__ dyl_t, const float* __restrict__ st,
    int f, int use_ws, int write_out, int row0, int tid)
{
    float* cf = f ? (float*)dout : (use_ws ? cws : (float*)0);
    __hip_bfloat16* cb = (__hip_bfloat16*)dout;

    int lane = tid & 63;
    int quad = lane >> 4;
    int m    = lane & 15;

    bf16x8 bw[4][2];
    float b1v[4], w2v[4];
#pragma unroll
    for (int nt = 0; nt < 4; ++nt) {
#pragma unroll
        for (int kb = 0; kb < 2; ++kb)
#pragma unroll
            for (int j = 0; j < 8; ++j) {
                int k = kb * 32 + quad * 8 + j;
                bw[nt][kb][j] = (__bf16)st[4160 + k * 64 + nt * 16 + m];
            }
        b1v[nt] = st[8256 + nt * 16 + m];
        w2v[nt] = st[8320 + nt * 16 + m];
    }

    int row = row0 + m;
    size_t base = (size_t)row * DIM;

    float hidf[2][8], dyf[2][8];
    const f32x4* dp = (const f32x4*)(dyl_t + m * 68);
    if (cf) {
        const f32x4* cp = (const f32x4*)(cf + base);
#pragma unroll
        for (int kb = 0; kb < 2; ++kb) {
            f32x4 a = cp[kb * 8 + quad * 2], b = cp[kb * 8 + quad * 2 + 1];
            f32x4 c = dp[kb * 8 + quad * 2], d = dp[kb * 8 + quad * 2 + 1];
#pragma unroll
            for (int j = 0; j < 4; ++j) {
                hidf[kb][j] = a[j]; hidf[kb][4 + j] = b[j];
                dyf[kb][j]  = c[j]; dyf[kb][4 + j]  = d[j];
            }
        }
    } else {
#pragma unroll
        for (int kb = 0; kb < 2; ++kb)
#pragma unroll
            for (int j = 0; j < 8; ++j) {
                int k = kb * 32 + quad * 8 + j;
                hidf[kb][j] = __bfloat162float(cb[base + k]);
                dyf[kb][j]  = dyl_t[m * 68 + k];
            }
    }

    bf16x8 ah[2], ad[2];
#pragma unroll
    for (int kb = 0; kb < 2; ++kb)
#pragma unroll
        for (int j = 0; j < 8; ++j) {
            ah[kb][j] = (__bf16)hidf[kb][j];
            ad[kb][j] = (__bf16)dyf[kb][j];
        }

    float zh[4] = {0.f, 0.f, 0.f, 0.f};
    float zd[4] = {0.f, 0.f, 0.f, 0.f};
#pragma unroll
    for (int nt = 0; nt < 4; ++nt) {
        f32x4 acch = {0.f, 0.f, 0.f, 0.f};
        f32x4 accd = {0.f, 0.f, 0.f, 0.f};
#pragma unroll
        for (int kb = 0; kb < 2; ++kb) {
            acch = __builtin_amdgcn_mfma_f32_16x16x32_bf16(ah[kb], bw[nt][kb], acch, 0, 0, 0);
            accd = __builtin_amdgcn_mfma_f32_16x16x32_bf16(ad[kb], bw[nt][kb], accd, 0, 0, 0);
        }
#pragma unroll
        for (int reg = 0; reg < 4; ++reg) {
            zh[reg] += tanhf(acch[reg] + b1v[nt]) * w2v[nt];
            zd[reg] += tanhf(accd[reg] + b1v[nt]) * w2v[nt];
        }
    }
    float s[4];
#pragma unroll
    for (int reg = 0; reg < 4; ++reg) {
#pragma unroll
        for (int off = 1; off < 16; off <<= 1) {
            zh[reg] += __shfl_xor(zh[reg], off, 64);
            zd[reg] += __shfl_xor(zd[reg], off, 64);
        }
        float mm = fmaxf(zh[reg], zd[reg]);
        float eh = expf(zh[reg] - mm), ed = expf(zd[reg] - mm);
        s[reg] = eh / (eh + ed);
    }
    int srcl = (m >> 2) * 16;
    float s0 = __shfl(s[0], srcl, 64), s1 = __shfl(s[1], srcl, 64);
    float s2 = __shfl(s[2], srcl, 64), s3 = __shfl(s[3], srcl, 64);
    int r3 = m & 3;
    float sv = (r3 == 0) ? s0 : (r3 == 1) ? s1 : (r3 == 2) ? s2 : s3;

    if (cf) {
        f32x4* cp = (f32x4*)(cf + base);
#pragma unroll
        for (int kb = 0; kb < 2; ++kb) {
            f32x4 v0, v1;
#pragma unroll
            for (int j = 0; j < 4; ++j) {
                v0[j] = sv * hidf[kb][j]     + (1.f - sv) * dyf[kb][j];
                v1[j] = sv * hidf[kb][4 + j] + (1.f - sv) * dyf[kb][4 + j];
            }
            cp[kb * 8 + quad * 2]     = v0;
            cp[kb * 8 + quad * 2 + 1] = v1;
            if (write_out && !f) {
#pragma unroll
                for (int j = 0; j < 4; ++j) {
                    int k = kb * 32 + quad * 8 + j;
                    cb[base + k]     = __float2bfloat16(v0[j]);
                    cb[base + k + 4] = __float2bfloat16(v1[j]);
                }
            }
        }
    } else {
#pragma unroll
        for (int kb = 0; kb < 2; ++kb)
#pragma unroll
            for (int j = 0; j < 8; ++j) {
                int k = kb * 32 + quad * 8 + j;
                float v = sv * hidf[kb][j] + (1.f - sv) * dyf[kb][j];
                cb[base + k] = __float2bfloat16(v);
            }
    }
}

// ---------------------------------------------------------------------------
// Prologue: zero counts slabs 0 and 1
// ---------------------------------------------------------------------------
__global__ __launch_bounds__(256) void k_zero2(int* __restrict__ c0, int* __restrict__ c1)
{
    if ((int)blockIdx.x < ZERO_BLKS) zero_body(c0, blockIdx.x, threadIdx.x);
    else                             zero_body(c1, blockIdx.x - ZERO_BLKS, threadIdx.x);
}

// ---------------------------------------------------------------------------
// Prologue: transform || append-E(0)
// ---------------------------------------------------------------------------
__global__ __launch_bounds__(256) void k_trans_appendE(
    const void* __restrict__ emb, const int* __restrict__ flag,
    const float* __restrict__ st, __hip_bfloat16* __restrict__ h,
    const int* __restrict__ nodes, const int* __restrict__ hyper,
    int* __restrict__ cnt, int* __restrict__ sn_pad)
{
    __shared__ float Wl[DIM * DIM];
    __shared__ float bl[DIM];
    if ((int)blockIdx.x < TR_BLOCKS) {
        for (int i = threadIdx.x; i < DIM * DIM; i += blockDim.x) Wl[i] = st[i];
        if (threadIdx.x < DIM) bl[threadIdx.x] = st[4096 + threadIdx.x];
        __syncthreads();
        int f = *flag;
        int wave = threadIdx.x >> 6, lane = threadIdx.x & 63;
        int nW = TR_BLOCKS * 4;
        for (int row = blockIdx.x * 4 + wave; row < N_USERS; row += nW) {
            size_t base = (size_t)row * DIM;
            float v = ld_in(emb, base + lane, f);
            float acc = bl[lane];
#pragma unroll
            for (int k = 0; k < DIM; ++k)
                acc += __shfl(v, k, 64) * Wl[k * DIM + lane];
            h[base + lane] = __float2bfloat16(fmaxf(acc, 0.f));
        }
    } else {
        appendE_body(nodes, hyper, cnt, sn_pad,
                     blockIdx.x - TR_BLOCKS, threadIdx.x);
    }
}

// ---------------------------------------------------------------------------
// KA(t): appendN(t) || appendE(t+1) || zero(slab t+2)  — pure build traffic,
// moved out of the gather kernels so BOTH heavyweight gathers can co-run in KB.
// ---------------------------------------------------------------------------
__global__ __launch_bounds__(256) void k_appends(
    const int* __restrict__ nodes0, const int* __restrict__ hyper0,
    int* __restrict__ cnt0, int* __restrict__ sh_pad, int nan_,
    const int* __restrict__ nodes1, const int* __restrict__ hyper1,
    int* __restrict__ cnt1, int* __restrict__ sn_pad, int nae,
    int* __restrict__ cnt_zero, int nz)
{
    int b = blockIdx.x, tid = threadIdx.x;
    if (b < nan_)
        appendN_body(nodes0, hyper0, cnt0, sh_pad, b, tid);
    else if (b < nan_ + nae)
        appendE_body(nodes1, hyper1, cnt1, sn_pad, b - nan_, tid);
    else if (nz)
        zero_body(cnt_zero, b - nan_ - nae, tid);
}

// ---------------------------------------------------------------------------
// KB(t): gnfuse(t) || ge(t+1) — the two latency-bound random-row gathers run
// CONCURRENTLY (double the outstanding L2-misses). e_buf double-buffered.
// gnfuse: 16 parallel chains/wave, wave-private LDS strip, fuse in-wave.
// ---------------------------------------------------------------------------
__global__ __launch_bounds__(256) void k_gnf_ge(
    const __hip_bfloat16* __restrict__ e_rd,
    const int* __restrict__ sh_pad, const int* __restrict__ cnt_n,
    void* __restrict__ dout, float* __restrict__ cws,
    const float* __restrict__ st, const int* __restrict__ flag,
    int use_ws, int to_carry, int write_out, int ngnf,
    const __hip_bfloat16* __restrict__ h,
    const int* __restrict__ sn_pad, const int* __restrict__ cnt_e,
    __hip_bfloat16* __restrict__ e_wr, int nge)
{
    __shared__ float dyl[4 * 16 * 68];
    int b = blockIdx.x, tid = threadIdx.x;
    if (b < ngnf) {
        int f = *flag;
        int lane = tid & 63, w = tid >> 6;
        int wid  = b * 4 + w;
        int row0 = wid * 16;
        if (row0 >= N_USERS) return;

        int pos[16], rem[16], cnt16[16]; float acc[16];
#pragma unroll
        for (int c = 0; c < 16; ++c) {
            int sg = row0 + c;
            int cc = (sg < N_USERS) ? cnt_n[sg] : 0;
            cnt16[c] = cc;
            pos[c]   = sg * CAP_N;
            rem[c]   = min(cc, CAP_N);
            acc[c]   = 0.f;
        }
        while (true) {
            bool any = false;
#pragma unroll
            for (int c = 0; c < 16; ++c) any = any || (rem[c] > 0);
            if (!any) break;
            int hy[16];
#pragma unroll
            for (int c = 0; c < 16; ++c)
                if (rem[c] > 0) hy[c] = sh_pad[pos[c]];
#pragma unroll
            for (int c = 0; c < 16; ++c)
                if (rem[c] > 0) {
                    acc[c] += __bfloat162float(e_rd[(size_t)hy[c] * DIM + lane]);
                    pos[c]++; rem[c]--;
                }
        }
#pragma unroll
        for (int c = 0; c < 16; ++c) {
            int sg = row0 + c;
            if (sg < N_USERS) {
                float v = acc[c] / (float)max(cnt16[c], 1);
                if (to_carry)
                    st_carry(dout, cws, (size_t)sg * DIM + lane, f, use_ws, v);
                else
                    dyl[(w * 16 + c) * 68 + lane] = v;
            }
        }
        if (!to_carry && row0 + 16 <= N_USERS)
            fu_tile(dout, cws, dyl + w * 16 * 68, st, f, use_ws,
                    write_out, row0, tid);
    } else if (b < ngnf + nge) {
        ge_body(h, sn_pad, cnt_e, e_wr, b - ngnf, tid);
    }
}

// ---------------------------------------------------------------------------
extern "C" void kernel_launch(void* const* d_in, const int* in_sizes, int n_in,
                              void* d_out, int out_size, void* d_ws,
                              size_t ws_size, hipStream_t stream)
{
    const void* user_emb = d_in[0];
    const void* W_conv   = d_in[1];
    const void* b_conv   = d_in[2];
    const void* fus_w1   = d_in[3];
    const void* fus_b1   = d_in[4];
    const void* fus_w2   = d_in[5];
    const void* fus_b2   = d_in[6];
    const int* edge_nodes = (const int*)d_in[7];
    const int* edge_hyper = (const int*)d_in[8];

    const size_t ND = (size_t)N_USERS * DIM;

    // ws layout (fp32 word offsets) — mandatory 51.43 MB (== R5 proven),
    // with optional carry 77.03 MB:
    //   0         : flag
    //   16        : st [8448]
    //   8464      : counts 3 slabs x 150016 ints (e[0,50K) | n[50K,150K))
    //   458512    : sn_pad int [50000*48]
    //   2858512   : sh_pad int [100000*36]
    //   6458512   : e_buf[0] bf16 [E*D]
    //   8058512   : e_buf[1] bf16 [E*D]
    //   9658512   : h bf16 [N*D]
    //   12858512  : optional fp32 carry [N*D]
    float* ws = (float*)d_ws;
    int*   flag   = (int*)ws;
    float* st     = ws + 16;
    int*   cnts[3];
    cnts[0] = (int*)(ws + 8464);
    cnts[1] = (int*)(ws + 8464 + 150016);
    cnts[2] = (int*)(ws + 8464 + 300032);
    int*   sn_pad = (int*)(ws + 458512);
    int*   sh_pad = (int*)(ws + 2858512);
    __hip_bfloat16* e_bufs[2];
    e_bufs[0] = (__hip_bfloat16*)(ws + 6458512);
    e_bufs[1] = (__hip_bfloat16*)(ws + 8058512);
    __hip_bfloat16* h = (__hip_bfloat16*)(ws + 9658512);
    float* carry_ws   = ws + 12858512;

    const size_t need_ws_carry = (12858512 + ND) * 4;
    const int use_ws = (ws_size >= need_ws_carry) ? 1 : 0;

    k_detect<<<1, 256, 0, stream>>>((const unsigned short*)user_emb, flag);
    k_convert_params<<<(8385 + 255) / 256, 256, 0, stream>>>(
        W_conv, b_conv, fus_w1, fus_b1, fus_w2, fus_b2, flag, st);

    // prologue: zero slabs 0,1; transform || append-E(0); ge(0) standalone
    k_zero2<<<2 * ZERO_BLKS, 256, 0, stream>>>(cnts[0], cnts[1]);
    k_trans_appendE<<<TR_BLOCKS + SC_BLOCKS, 256, 0, stream>>>(
        user_emb, flag, st, h, edge_nodes, edge_hyper, cnts[0], sn_pad);
    k_gnf_ge<<<GE_BLOCKS, 256, 0, stream>>>(
        e_bufs[0], sh_pad, cnts[0] + E_HYPER, d_out, carry_ws, st, flag,
        use_ws, 0, 0, 0 /*ngnf=0*/,
        h, sn_pad, cnts[0], e_bufs[0], GE_BLOCKS);

    for (int t = 0; t < T_STEPS; ++t) {
        const int* nodes0 = edge_nodes + (size_t)t * NNZ_E;
        const int* hyper0 = edge_hyper + (size_t)t * NNZ_E;
        const int* nodes1 = edge_nodes + (size_t)(t + 1) * NNZ_E;
        const int* hyper1 = edge_hyper + (size_t)(t + 1) * NNZ_E;
        int c3 = t % 3, n3 = (t + 1) % 3, z3 = (t + 2) % 3;

        // KA(t): appendN(t) || appendE(t+1) || zero(slab t+2)
        int nan_ = SC_BLOCKS;
        int nae  = (t < T_STEPS - 1) ? SC_BLOCKS : 0;
        int nz   = (t < T_STEPS - 2) ? ZERO_BLKS : 0;
        k_appends<<<nan_ + nae + nz, 256, 0, stream>>>(
            nodes0, hyper0, cnts[c3], sh_pad, nan_,
            nodes1, hyper1, cnts[n3], sn_pad, nae,
            cnts[z3], nz);

        // KB(t): gnfuse(t) || ge(t+1)
        int nge = (t < T_STEPS - 1) ? GE_BLOCKS : 0;
        k_gnf_ge<<<GNF_BLOCKS + nge, 256, 0, stream>>>(
            e_bufs[t & 1], sh_pad, cnts[c3] + E_HYPER,
            d_out, carry_ws, st, flag, use_ws,
            (t == 0) ? 1 : 0, (t == T_STEPS - 1) ? 1 : 0, GNF_BLOCKS,
            h, sn_pad, cnts[n3], e_bufs[(t + 1) & 1], nge);
    }
}

// Round 7
// 2324.932 us; speedup vs baseline: 1.2461x; 1.2461x over previous
//
#include <hip/hip_runtime.h>
#include <hip/hip_bf16.h>

#define N_USERS 100000
#define E_HYPER 50000
#define NNZ_E   800000
#define T_STEPS 8
#define DIM     64

#define CAP_E   48
#define CAP_N   40      // 2 buckets x 20
#define BUCK_N  20
#define E_HALF  25000   // e-slice split: bucket 0 = hy<25000 (3.2MB, L2-fits)

#define TR_BLOCKS  1024
#define GE_BLOCKS  1563
#define GNF_BLOCKS 1563
#define CNT_SLAB   250016   // e[0,50000) | n 2-per-node [50000,250000)
#define ZERO_BLKS  245      // 245*256 int4 = 62720 >= 62504

#define SC_PARTS   8
#define SC_SUB     256
#define SC_BLOCKS  (SC_PARTS * SC_SUB)   // 2048
#define SC_CHUNK   (NNZ_E / SC_SUB)      // 3125
#define E_SLICE    (E_HYPER / SC_PARTS)  // 6250
#define N_SLICE    (N_USERS / SC_PARTS)  // 12500

typedef __bf16 bf16x8 __attribute__((ext_vector_type(8)));
typedef float  f32x4  __attribute__((ext_vector_type(4)));

// ---------------------------------------------------------------------------
__device__ __forceinline__ float ld_in(const void* p, size_t i, int f32)
{
    return f32 ? ((const float*)p)[i]
               : __bfloat162float(((const __hip_bfloat16*)p)[i]);
}

__device__ __forceinline__ void st_carry(void* out, float* cws, size_t i,
                                         int f, int use_ws, float v)
{
    if (f) { ((float*)out)[i] = v; return; }
    if (use_ws) { cws[i] = v; return; }
    ((__hip_bfloat16*)out)[i] = __float2bfloat16(v);
}

// ---------------------------------------------------------------------------
// Kernel 0: input dtype detector
// ---------------------------------------------------------------------------
__global__ void k_detect(const unsigned short* __restrict__ raw, int* __restrict__ flag)
{
    __shared__ int cnt;
    if (threadIdx.x == 0) cnt = 0;
    __syncthreads();
    int c = 0;
    for (int i = threadIdx.x; i < 4096; i += blockDim.x) {
        int e = (raw[i] >> 7) & 0xFF;
        if (e > 126) c++;
    }
    atomicAdd(&cnt, c);
    __syncthreads();
    if (threadIdx.x == 0) *flag = (cnt > 64) ? 1 : 0;
}

// ---------------------------------------------------------------------------
// Kernel 0b: params -> fp32 staging
// st: W[0,4096) b[4096,4160) w1[4160,8256) b1[8256,8320) w2[8320,8384) b2[8384]
// ---------------------------------------------------------------------------
__global__ void k_convert_params(
    const void* W, const void* b, const void* w1, const void* b1,
    const void* w2, const void* b2, const int* __restrict__ flag,
    float* __restrict__ st)
{
    int f = *flag;
    int i = blockIdx.x * blockDim.x + threadIdx.x;
    if (i < 4096)          st[i] = ld_in(W,  i,        f);
    else if (i < 4160)     st[i] = ld_in(b,  i - 4096, f);
    else if (i < 8256)     st[i] = ld_in(w1, i - 4160, f);
    else if (i < 8320)     st[i] = ld_in(b1, i - 8256, f);
    else if (i < 8384)     st[i] = ld_in(w2, i - 8320, f);
    else if (i == 8384)    st[i] = ld_in(b2, 0,        f);
}

// ---------------------------------------------------------------------------
// Padded atomic-append (XCD-partitioned writes).
// counts slab: [0,E_HYPER) per-hyperedge; [E_HYPER + nd*2 + b] per-node-bucket.
// appendN buckets members by e-slice so gather_n can do 2 L2-resident passes.
// ---------------------------------------------------------------------------
__device__ __forceinline__ void appendE_body(
    const int* __restrict__ nodes, const int* __restrict__ hyper,
    int* __restrict__ cnt, int* __restrict__ sn_pad, int bid, int tid)
{
    int part = bid & (SC_PARTS - 1);
    int sub  = bid >> 3;
    int elo  = part * E_SLICE;
    int i0   = sub * SC_CHUNK;
    for (int i = i0 + tid; i < i0 + SC_CHUNK; i += 256) {
        int hy = hyper[i];
        if ((unsigned)(hy - elo) < (unsigned)E_SLICE) {
            int r = atomicAdd(&cnt[hy], 1);
            if (r < CAP_E) sn_pad[hy * CAP_E + r] = nodes[i];
        }
    }
}

__device__ __forceinline__ void appendN_body(
    const int* __restrict__ nodes, const int* __restrict__ hyper,
    int* __restrict__ cnt, int* __restrict__ sh_pad, int bid, int tid)
{
    int part = bid & (SC_PARTS - 1);
    int sub  = bid >> 3;
    int nlo  = part * N_SLICE;
    int i0   = sub * SC_CHUNK;
    for (int i = i0 + tid; i < i0 + SC_CHUNK; i += 256) {
        int nd = nodes[i];
        if ((unsigned)(nd - nlo) < (unsigned)N_SLICE) {
            int hy = hyper[i];
            int bk = (hy >= E_HALF) ? 1 : 0;
            int r = atomicAdd(&cnt[E_HYPER + nd * 2 + bk], 1);
            if (r < BUCK_N) sh_pad[nd * CAP_N + bk * BUCK_N + r] = hy;
        }
    }
}

__device__ __forceinline__ void zero_body(int* __restrict__ buf, int b, int tid)
{
    int idx = b * 256 + tid;
    if (idx < CNT_SLAB / 4) ((int4*)buf)[idx] = make_int4(0, 0, 0, 0);
}

// ---------------------------------------------------------------------------
// gather_e body (padded CSR, 8 segments/wave)
// ---------------------------------------------------------------------------
__device__ __forceinline__ void ge_body(
    const __hip_bfloat16* __restrict__ h,
    const int* __restrict__ sn_pad, const int* __restrict__ cnt_e,
    __hip_bfloat16* __restrict__ e, int bid, int tid)
{
    int lane = tid & 63;
    int wid = bid * 4 + (tid >> 6);
    int nW  = GE_BLOCKS * 4;
    for (int s0 = wid * 8; s0 < E_HYPER; s0 += nW * 8) {
        int pos[8], end8[8], cnt8[8]; float acc[8];
#pragma unroll
        for (int c = 0; c < 8; ++c) {
            int sg = s0 + c;
            int cc = (sg < E_HYPER) ? cnt_e[sg] : 0;
            cnt8[c] = cc;
            pos[c]  = sg * CAP_E;
            end8[c] = pos[c] + min(cc, CAP_E);
            acc[c]  = 0.f;
        }
        while (true) {
            bool any = false;
#pragma unroll
            for (int c = 0; c < 8; ++c) any = any || (pos[c] < end8[c]);
            if (!any) break;
            int id[8];
#pragma unroll
            for (int c = 0; c < 8; ++c)
                if (pos[c] < end8[c]) id[c] = sn_pad[pos[c]];
#pragma unroll
            for (int c = 0; c < 8; ++c)
                if (pos[c] < end8[c]) {
                    acc[c] += __bfloat162float(h[(size_t)id[c] * DIM + lane]);
                    pos[c]++;
                }
        }
#pragma unroll
        for (int c = 0; c < 8; ++c) {
            int sg = s0 + c;
            if (sg < E_HYPER)
                e[(size_t)sg * DIM + lane] =
                    __float2bfloat16(acc[c] / (float)max(cnt8[c], 1));
        }
    }
}

// ---------------------------------------------------------------------------
// fuse tile: ONE 16-row tile at rows [row0,row0+16), dy from LDS (stride 68)
// ---------------------------------------------------------------------------
__device__ __forceinline__ void fu_tile(
    void* __restrict__ dout, float* __restrict__ cws,
    const float* __restrict__ dyl_t, const float* __restrict__ st,
    int f, int use_ws, int write_out, int row0, int tid)
{
    float* cf = f ? (float*)dout : (use_ws ? cws : (float*)0);
    __hip_bfloat16* cb = (__hip_bfloat16*)dout;

    int lane = tid & 63;
    int quad = lane >> 4;
    int m    = lane & 15;

    bf16x8 bw[4][2];
    float b1v[4], w2v[4];
#pragma unroll
    for (int nt = 0; nt < 4; ++nt) {
#pragma unroll
        for (int kb = 0; kb < 2; ++kb)
#pragma unroll
            for (int j = 0; j < 8; ++j) {
                int k = kb * 32 + quad * 8 + j;
                bw[nt][kb][j] = (__bf16)st[4160 + k * 64 + nt * 16 + m];
            }
        b1v[nt] = st[8256 + nt * 16 + m];
        w2v[nt] = st[8320 + nt * 16 + m];
    }

    int row = row0 + m;
    size_t base = (size_t)row * DIM;

    float hidf[2][8], dyf[2][8];
    const f32x4* dp = (const f32x4*)(dyl_t + m * 68);
    if (cf) {
        const f32x4* cp = (const f32x4*)(cf + base);
#pragma unroll
        for (int kb = 0; kb < 2; ++kb) {
            f32x4 a = cp[kb * 8 + quad * 2], b = cp[kb * 8 + quad * 2 + 1];
            f32x4 c = dp[kb * 8 + quad * 2], d = dp[kb * 8 + quad * 2 + 1];
#pragma unroll
            for (int j = 0; j < 4; ++j) {
                hidf[kb][j] = a[j]; hidf[kb][4 + j] = b[j];
                dyf[kb][j]  = c[j]; dyf[kb][4 + j]  = d[j];
            }
        }
    } else {
#pragma unroll
        for (int kb = 0; kb < 2; ++kb)
#pragma unroll
            for (int j = 0; j < 8; ++j) {
                int k = kb * 32 + quad * 8 + j;
                hidf[kb][j] = __bfloat162float(cb[base + k]);
                dyf[kb][j]  = dyl_t[m * 68 + k];
            }
    }

    bf16x8 ah[2], ad[2];
#pragma unroll
    for (int kb = 0; kb < 2; ++kb)
#pragma unroll
        for (int j = 0; j < 8; ++j) {
            ah[kb][j] = (__bf16)hidf[kb][j];
            ad[kb][j] = (__bf16)dyf[kb][j];
        }

    float zh[4] = {0.f, 0.f, 0.f, 0.f};
    float zd[4] = {0.f, 0.f, 0.f, 0.f};
#pragma unroll
    for (int nt = 0; nt < 4; ++nt) {
        f32x4 acch = {0.f, 0.f, 0.f, 0.f};
        f32x4 accd = {0.f, 0.f, 0.f, 0.f};
#pragma unroll
        for (int kb = 0; kb < 2; ++kb) {
            acch = __builtin_amdgcn_mfma_f32_16x16x32_bf16(ah[kb], bw[nt][kb], acch, 0, 0, 0);
            accd = __builtin_amdgcn_mfma_f32_16x16x32_bf16(ad[kb], bw[nt][kb], accd, 0, 0, 0);
        }
#pragma unroll
        for (int reg = 0; reg < 4; ++reg) {
            zh[reg] += tanhf(acch[reg] + b1v[nt]) * w2v[nt];
            zd[reg] += tanhf(accd[reg] + b1v[nt]) * w2v[nt];
        }
    }
    float s[4];
#pragma unroll
    for (int reg = 0; reg < 4; ++reg) {
#pragma unroll
        for (int off = 1; off < 16; off <<= 1) {
            zh[reg] += __shfl_xor(zh[reg], off, 64);
            zd[reg] += __shfl_xor(zd[reg], off, 64);
        }
        float mm = fmaxf(zh[reg], zd[reg]);
        float eh = expf(zh[reg] - mm), ed = expf(zd[reg] - mm);
        s[reg] = eh / (eh + ed);
    }
    int srcl = (m >> 2) * 16;
    float s0 = __shfl(s[0], srcl, 64), s1 = __shfl(s[1], srcl, 64);
    float s2 = __shfl(s[2], srcl, 64), s3 = __shfl(s[3], srcl, 64);
    int r3 = m & 3;
    float sv = (r3 == 0) ? s0 : (r3 == 1) ? s1 : (r3 == 2) ? s2 : s3;

    if (cf) {
        f32x4* cp = (f32x4*)(cf + base);
#pragma unroll
        for (int kb = 0; kb < 2; ++kb) {
            f32x4 v0, v1;
#pragma unroll
            for (int j = 0; j < 4; ++j) {
                v0[j] = sv * hidf[kb][j]     + (1.f - sv) * dyf[kb][j];
                v1[j] = sv * hidf[kb][4 + j] + (1.f - sv) * dyf[kb][4 + j];
            }
            cp[kb * 8 + quad * 2]     = v0;
            cp[kb * 8 + quad * 2 + 1] = v1;
            if (write_out && !f) {
#pragma unroll
                for (int j = 0; j < 4; ++j) {
                    int k = kb * 32 + quad * 8 + j;
                    cb[base + k]     = __float2bfloat16(v0[j]);
                    cb[base + k + 4] = __float2bfloat16(v1[j]);
                }
            }
        }
    } else {
#pragma unroll
        for (int kb = 0; kb < 2; ++kb)
#pragma unroll
            for (int j = 0; j < 8; ++j) {
                int k = kb * 32 + quad * 8 + j;
                float v = sv * hidf[kb][j] + (1.f - sv) * dyf[kb][j];
                cb[base + k] = __float2bfloat16(v);
            }
    }
}

// ---------------------------------------------------------------------------
// Prologue: zero counts slabs 0 and 1
// ---------------------------------------------------------------------------
__global__ __launch_bounds__(256) void k_zero2(int* __restrict__ c0, int* __restrict__ c1)
{
    if ((int)blockIdx.x < ZERO_BLKS) zero_body(c0, blockIdx.x, threadIdx.x);
    else                             zero_body(c1, blockIdx.x - ZERO_BLKS, threadIdx.x);
}

// ---------------------------------------------------------------------------
// Prologue: transform || append-E(0)
// ---------------------------------------------------------------------------
__global__ __launch_bounds__(256) void k_trans_appendE(
    const void* __restrict__ emb, const int* __restrict__ flag,
    const float* __restrict__ st, __hip_bfloat16* __restrict__ h,
    const int* __restrict__ nodes, const int* __restrict__ hyper,
    int* __restrict__ cnt, int* __restrict__ sn_pad)
{
    __shared__ float Wl[DIM * DIM];
    __shared__ float bl[DIM];
    if ((int)blockIdx.x < TR_BLOCKS) {
        for (int i = threadIdx.x; i < DIM * DIM; i += blockDim.x) Wl[i] = st[i];
        if (threadIdx.x < DIM) bl[threadIdx.x] = st[4096 + threadIdx.x];
        __syncthreads();
        int f = *flag;
        int wave = threadIdx.x >> 6, lane = threadIdx.x & 63;
        int nW = TR_BLOCKS * 4;
        for (int row = blockIdx.x * 4 + wave; row < N_USERS; row += nW) {
            size_t base = (size_t)row * DIM;
            float v = ld_in(emb, base + lane, f);
            float acc = bl[lane];
#pragma unroll
            for (int k = 0; k < DIM; ++k)
                acc += __shfl(v, k, 64) * Wl[k * DIM + lane];
            h[base + lane] = __float2bfloat16(fmaxf(acc, 0.f));
        }
    } else {
        appendE_body(nodes, hyper, cnt, sn_pad,
                     blockIdx.x - TR_BLOCKS, threadIdx.x);
    }
}

// ---------------------------------------------------------------------------
// KA(t): gather_e(t) || append-N(t)  (R5-proven pairing)
// ---------------------------------------------------------------------------
__global__ __launch_bounds__(256) void k_ge_appendN(
    const __hip_bfloat16* __restrict__ h,
    const int* __restrict__ sn_pad, const int* __restrict__ cnt_cur,
    __hip_bfloat16* __restrict__ e,
    const int* __restrict__ nodes, const int* __restrict__ hyper,
    int* __restrict__ cnt_w, int* __restrict__ sh_pad)
{
    if ((int)blockIdx.x < GE_BLOCKS)
        ge_body(h, sn_pad, cnt_cur, e, blockIdx.x, threadIdx.x);
    else
        appendN_body(nodes, hyper, cnt_w, sh_pad,
                     blockIdx.x - GE_BLOCKS, threadIdx.x);
}

// ---------------------------------------------------------------------------
// KB(t): gnfuse(t) || append-E(t+1) || zero(slab t+2)
// gnfuse: 16 parallel chains/wave; TWO e-slice passes — pass b reads only
// e-rows in a 3.2MB half (fits each XCD's 4MB L2): first touch fills, rest
// hit. acc persists in registers across passes. Fuse in-wave from LDS strip.
// ---------------------------------------------------------------------------
__global__ __launch_bounds__(256) void k_gnfuse(
    const __hip_bfloat16* __restrict__ e,
    const int* __restrict__ sh_pad, const int* __restrict__ cnt_n,
    void* __restrict__ dout, float* __restrict__ cws,
    const float* __restrict__ st, const int* __restrict__ flag,
    int use_ws, int to_carry, int write_out,
    const int* __restrict__ nodes1, const int* __restrict__ hyper1,
    int* __restrict__ cnt_nxt, int* __restrict__ sn_pad, int nsc,
    int* __restrict__ cnt_zero, int nzero)
{
    __shared__ float dyl[4 * 16 * 68];   // 4 wave-private strips
    int b = blockIdx.x, tid = threadIdx.x;
    if (b < GNF_BLOCKS) {
        int f = *flag;
        int lane = tid & 63, w = tid >> 6;
        int wid  = b * 4 + w;
        int row0 = wid * 16;
        if (row0 >= N_USERS) return;

        int pos[16], rem[16], tot[16]; float acc[16];
#pragma unroll
        for (int c = 0; c < 16; ++c) { acc[c] = 0.f; tot[c] = 0; }

        for (int bk = 0; bk < 2; ++bk) {
#pragma unroll
            for (int c = 0; c < 16; ++c) {
                int sg = row0 + c;
                int cc = (sg < N_USERS) ? cnt_n[sg * 2 + bk] : 0;
                tot[c] += cc;
                pos[c]  = sg * CAP_N + bk * BUCK_N;
                rem[c]  = min(cc, BUCK_N);
            }
            while (true) {
                bool any = false;
#pragma unroll
                for (int c = 0; c < 16; ++c) any = any || (rem[c] > 0);
                if (!any) break;
                int hy[16];
#pragma unroll
                for (int c = 0; c < 16; ++c)
                    if (rem[c] > 0) hy[c] = sh_pad[pos[c]];
#pragma unroll
                for (int c = 0; c < 16; ++c)
                    if (rem[c] > 0) {
                        acc[c] += __bfloat162float(e[(size_t)hy[c] * DIM + lane]);
                        pos[c]++; rem[c]--;
                    }
            }
        }
#pragma unroll
        for (int c = 0; c < 16; ++c) {
            int sg = row0 + c;
            if (sg < N_USERS) {
                float v = acc[c] / (float)max(tot[c], 1);
                if (to_carry)
                    st_carry(dout, cws, (size_t)sg * DIM + lane, f, use_ws, v);
                else
                    dyl[(w * 16 + c) * 68 + lane] = v;
            }
        }
        if (!to_carry && row0 + 16 <= N_USERS)
            fu_tile(dout, cws, dyl + w * 16 * 68, st, f, use_ws,
                    write_out, row0, tid);
    } else if (b < GNF_BLOCKS + nsc) {
        appendE_body(nodes1, hyper1, cnt_nxt, sn_pad, b - GNF_BLOCKS, tid);
    } else if (nzero) {
        zero_body(cnt_zero, b - GNF_BLOCKS - nsc, tid);
    }
}

// ---------------------------------------------------------------------------
extern "C" void kernel_launch(void* const* d_in, const int* in_sizes, int n_in,
                              void* d_out, int out_size, void* d_ws,
                              size_t ws_size, hipStream_t stream)
{
    const void* user_emb = d_in[0];
    const void* W_conv   = d_in[1];
    const void* b_conv   = d_in[2];
    const void* fus_w1   = d_in[3];
    const void* fus_b1   = d_in[4];
    const void* fus_w2   = d_in[5];
    const void* fus_b2   = d_in[6];
    const int* edge_nodes = (const int*)d_in[7];
    const int* edge_hyper = (const int*)d_in[8];

    const size_t ND = (size_t)N_USERS * DIM;

    // ws layout (fp32 word offsets) — mandatory 41.4 MB, with carry 67.0 MB:
    //   0         : flag
    //   16        : st [8448]
    //   8464      : counts 3 slabs x 250016 ints (e[0,50K) | n-bucket pairs)
    //   758512    : sn_pad int [50000*48]
    //   3158512   : sh_pad int [100000*40] (2 buckets x 20 per node)
    //   7158512   : e_buf bf16 [E*D]
    //   8758512   : h bf16 [N*D]
    //   10358512  : optional fp32 carry [N*D]
    float* ws = (float*)d_ws;
    int*   flag   = (int*)ws;
    float* st     = ws + 16;
    int*   cnts[3];
    cnts[0] = (int*)(ws + 8464);
    cnts[1] = (int*)(ws + 8464 + CNT_SLAB);
    cnts[2] = (int*)(ws + 8464 + 2 * CNT_SLAB);
    int*   sn_pad = (int*)(ws + 758512);
    int*   sh_pad = (int*)(ws + 3158512);
    __hip_bfloat16* e_buf = (__hip_bfloat16*)(ws + 7158512);
    __hip_bfloat16* h     = (__hip_bfloat16*)(ws + 8758512);
    float* carry_ws       = ws + 10358512;

    const size_t need_ws_carry = (10358512 + ND) * 4;
    const int use_ws = (ws_size >= need_ws_carry) ? 1 : 0;

    k_detect<<<1, 256, 0, stream>>>((const unsigned short*)user_emb, flag);
    k_convert_params<<<(8385 + 255) / 256, 256, 0, stream>>>(
        W_conv, b_conv, fus_w1, fus_b1, fus_w2, fus_b2, flag, st);

    // prologue: zero slabs 0,1; transform || append-E(0)
    k_zero2<<<2 * ZERO_BLKS, 256, 0, stream>>>(cnts[0], cnts[1]);
    k_trans_appendE<<<TR_BLOCKS + SC_BLOCKS, 256, 0, stream>>>(
        user_emb, flag, st, h, edge_nodes, edge_hyper, cnts[0], sn_pad);

    for (int t = 0; t < T_STEPS; ++t) {
        const int* nodes0 = edge_nodes + (size_t)t * NNZ_E;
        const int* hyper0 = edge_hyper + (size_t)t * NNZ_E;
        const int* nodes1 = edge_nodes + (size_t)(t + 1) * NNZ_E;
        const int* hyper1 = edge_hyper + (size_t)(t + 1) * NNZ_E;
        int c3 = t % 3, n3 = (t + 1) % 3, z3 = (t + 2) % 3;

        // KA: ge(t) || append-N(t)  (sh_pad for list t, read next dispatch)
        k_ge_appendN<<<GE_BLOCKS + SC_BLOCKS, 256, 0, stream>>>(
            h, sn_pad, cnts[c3], e_buf, nodes0, hyper0, cnts[c3], sh_pad);

        // KB: gnfuse(t) || append-E(t+1) || zero(slab t+2)
        int nsc = (t < T_STEPS - 1) ? SC_BLOCKS : 0;
        int nz  = (t < T_STEPS - 2) ? ZERO_BLKS : 0;
        k_gnfuse<<<GNF_BLOCKS + nsc + nz, 256, 0, stream>>>(
            e_buf, sh_pad, cnts[c3] + E_HYPER,
            d_out, carry_ws, st, flag, use_ws,
            (t == 0) ? 1 : 0, (t == T_STEPS - 1) ? 1 : 0,
            nodes1, hyper1, cnts[n3], sn_pad, nsc, cnts[z3], nz);
    }
}